// Round 2
// baseline (4536.242 us; speedup 1.0000x reference)
//
#include <hip/hip_runtime.h>

// Involution: fused kernel-generation + 7x7 depthwise involution.
// Shapes (fixed by reference): x (B,256,64,64) f32, reduce_w (64,256),
// bn_* (64,), kproj_w (12544,64), kproj_b (12544,). out (B,256,64,64) f32.
//
// R1 note: __launch_bounds__(256,2) capped VGPRs at 128 -> acc[49] spilled to
// scratch (832 MB write traffic, matched 131072 thr x 32 gi x 49 x 4B).
// Fix: no min-wave bound; LDS (70KB) already limits to 2 blocks/CU anyway.

#define C_    256
#define HID_  64
#define KS_   7
#define KK_   49
#define G_    256
#define H_    64
#define W_    64
#define HW_   4096
#define GRP_TILE 32
#define PAD_  4

__global__ __launch_bounds__(256) void invol_fused(
    const float* __restrict__ x,
    const float* __restrict__ reduce_w,
    const float* __restrict__ bn_gamma,
    const float* __restrict__ bn_beta,
    const float* __restrict__ bn_mean,
    const float* __restrict__ bn_var,
    const float* __restrict__ kw,
    const float* __restrict__ kb,
    float* __restrict__ out)
{
    // Transposed reduce_w: rwT[k][o] = reduce_w[o][k]. Row stride 68 floats
    // (272 B, 16B-aligned for b128 broadcast reads).
    __shared__ float rwT[C_][HID_ + PAD_];
    __shared__ float bns[HID_];
    __shared__ float bnb[HID_];

    const int tid = threadIdx.x;
    const int b  = blockIdx.z;
    const int g0 = blockIdx.y * GRP_TILE;
    const int p  = blockIdx.x * 256 + tid;   // pixel index in HW
    const int py = p >> 6;
    const int px = p & 63;

    // ---- stage reduce_w transposed (coalesced global reads) ----
    #pragma unroll 1
    for (int o = 0; o < HID_; ++o) {
        rwT[tid][o] = reduce_w[o * C_ + tid];   // tid = k
    }
    if (tid < HID_) {
        float inv = bn_gamma[tid] * rsqrtf(bn_var[tid] + 1e-5f);
        bns[tid] = inv;
        bnb[tid] = bn_beta[tid] - bn_mean[tid] * inv;
    }
    __syncthreads();

    // ---- per-pixel hidden vector: hv[o] = relu(bn(sum_k x[k]*W[o][k])) ----
    float hv[HID_];
    #pragma unroll
    for (int o = 0; o < HID_; ++o) hv[o] = 0.f;

    const float* xb = x + (size_t)b * C_ * HW_ + p;
    #pragma unroll 4
    for (int k = 0; k < C_; ++k) {
        float xk = xb[(size_t)k * HW_];                 // coalesced across lanes
        const float4* wr = (const float4*)&rwT[k][0];   // broadcast LDS reads
        #pragma unroll
        for (int o4 = 0; o4 < HID_ / 4; ++o4) {
            float4 w = wr[o4];
            hv[o4*4+0] = fmaf(xk, w.x, hv[o4*4+0]);
            hv[o4*4+1] = fmaf(xk, w.y, hv[o4*4+1]);
            hv[o4*4+2] = fmaf(xk, w.z, hv[o4*4+2]);
            hv[o4*4+3] = fmaf(xk, w.w, hv[o4*4+3]);
        }
    }
    #pragma unroll
    for (int o = 0; o < HID_; ++o) {
        hv[o] = fmaxf(fmaf(hv[o], bns[o], bnb[o]), 0.f);
    }

    // ---- per group: 49 taps -> normalize -> involution ----
    #pragma unroll 1
    for (int gi = 0; gi < GRP_TILE; ++gi) {
        const int g = g0 + gi;
        const float* __restrict__ kwg = kw + (size_t)g * KK_ * HID_;
        const float* __restrict__ kbg = kb + (size_t)g * KK_;

        float acc[KK_];
        #pragma unroll
        for (int t = 0; t < KK_; ++t) {
            float a = kbg[t];
            const float4* row = (const float4*)(kwg + t * HID_);
            #pragma unroll
            for (int k4 = 0; k4 < HID_ / 4; ++k4) {
                float4 w = row[k4];
                a = fmaf(w.x, hv[k4*4+0], a);
                a = fmaf(w.y, hv[k4*4+1], a);
                a = fmaf(w.z, hv[k4*4+2], a);
                a = fmaf(w.w, hv[k4*4+3], a);
            }
            acc[t] = a;
        }

        // zero-mean + L2 norm over the 49 taps (scale folded into epilogue)
        float mean = 0.f;
        #pragma unroll
        for (int t = 0; t < KK_; ++t) mean += acc[t];
        mean *= (1.f / 49.f);
        float ss = 0.f;
        #pragma unroll
        for (int t = 0; t < KK_; ++t) {
            acc[t] -= mean;
            ss = fmaf(acc[t], acc[t], ss);
        }
        float inv = 1.f / fmaxf(sqrtf(ss), 1e-6f);

        // 7x7 involution with zero padding
        const float* __restrict__ xg = x + ((size_t)(b * G_ + g)) * HW_;
        float oacc = 0.f;
        #pragma unroll
        for (int i = 0; i < KS_; ++i) {
            int y = py + i - 3;
            bool rok = ((unsigned)y < (unsigned)H_);
            const float* xrow = xg + y * W_;
            #pragma unroll
            for (int j = 0; j < KS_; ++j) {
                int xx = px + j - 3;
                bool ok = rok && ((unsigned)xx < (unsigned)W_);
                float v = ok ? xrow[xx] : 0.f;
                oacc = fmaf(v, acc[i*7+j], oacc);
            }
        }
        out[((size_t)(b * G_ + g)) * HW_ + p] = oacc * inv;
    }
}

extern "C" void kernel_launch(void* const* d_in, const int* in_sizes, int n_in,
                              void* d_out, int out_size, void* d_ws, size_t ws_size,
                              hipStream_t stream) {
    const float* x        = (const float*)d_in[0];
    const float* reduce_w = (const float*)d_in[1];
    const float* bn_gamma = (const float*)d_in[2];
    const float* bn_beta  = (const float*)d_in[3];
    const float* bn_mean  = (const float*)d_in[4];
    const float* bn_var   = (const float*)d_in[5];
    const float* kproj_w  = (const float*)d_in[6];
    const float* kproj_b  = (const float*)d_in[7];
    float* out = (float*)d_out;

    const int B = in_sizes[0] / (C_ * HW_);

    dim3 grid(HW_ / 256, G_ / GRP_TILE, B);
    dim3 block(256);
    invol_fused<<<grid, block, 0, stream>>>(x, reduce_w, bn_gamma, bn_beta,
                                            bn_mean, bn_var, kproj_w, kproj_b, out);
}

// Round 3
// 232.309 us; speedup vs baseline: 19.5268x; 19.5268x over previous
//
#include <hip/hip_runtime.h>

// Involution via bf16 MFMA tap-GEMM.
// Pipeline: prep (kw->bf16 B-layout, rw->transposed+BN-folded) -> hv (hidden
// vec per pixel, bf16) -> main (MFMA ker-GEMM + L2 norm + 7x7 involution).
// R2 lesson: VALU formulation is latency-bound on per-lane kw broadcast loads
// (every lane consumes all 3136 B-elems per group). MFMA distributes the
// B-fragment across the wave -> 64x less operand traffic + matrix pipe.

#define C_    256
#define HID_  64
#define KS_   7
#define KK_   49
#define G_    256
#define H_    64
#define W_    64
#define HW_   4096
#define BN_EPS 1e-5f

typedef __attribute__((ext_vector_type(8))) short bf16x8;
typedef __attribute__((ext_vector_type(4))) float f32x4;

__device__ __forceinline__ ushort f2bf(float f) {
    unsigned u = __float_as_uint(f);
    unsigned r = (u + 0x7fffu + ((u >> 16) & 1u)) >> 16;   // RNE
    return (ushort)r;
}

// ---------------------------------------------------------------- prep ----
// blocks 0..255: kwb[g][t][k] bf16, t padded 49->64 with zeros.
// block 256:     rwT[k][o] = reduce_w[o][k] * bn_inv[o];  betp[o].
__global__ __launch_bounds__(256) void prep_kernel(
    const float* __restrict__ kw, const float* __restrict__ reduce_w,
    const float* __restrict__ bn_gamma, const float* __restrict__ bn_beta,
    const float* __restrict__ bn_mean, const float* __restrict__ bn_var,
    ushort* __restrict__ kwb, float* __restrict__ rwT, float* __restrict__ betp)
{
    if (blockIdx.x < 256) {
        int idx  = blockIdx.x * 256 + threadIdx.x;   // [0, 65536)
        int base = idx * 16;                         // 16 bf16 elems each
        int g    = base >> 12;
        int rem  = base & 4095;
        int t    = rem >> 6;
        int k0   = rem & 63;
        union { ushort s[16]; uint4 v[2]; } u;
        if (t < KK_) {
            const float* src = kw + ((size_t)(g * KK_ + t)) * HID_ + k0;
            #pragma unroll
            for (int i = 0; i < 16; ++i) u.s[i] = f2bf(src[i]);
        } else {
            #pragma unroll
            for (int i = 0; i < 16; ++i) u.s[i] = 0;
        }
        uint4* dst = (uint4*)(kwb + base);
        dst[0] = u.v[0];
        dst[1] = u.v[1];
    } else {
        int k = threadIdx.x;                         // [0,256)
        #pragma unroll 1
        for (int o = 0; o < HID_; ++o) {
            float inv = bn_gamma[o] * rsqrtf(bn_var[o] + BN_EPS);
            rwT[k * HID_ + o] = reduce_w[o * C_ + k] * inv;
        }
        if (k < HID_) {
            float inv = bn_gamma[k] * rsqrtf(bn_var[k] + BN_EPS);
            betp[k] = bn_beta[k] - bn_mean[k] * inv;
        }
    }
}

// ------------------------------------------------------------------ hv ----
// hv[p][o] = relu(sum_k x[k][p] * rwT[k][o] + betp[o]) in bf16.
// wave = o-quarter (16 outputs); weights are wave-uniform -> s_loads.
__global__ __launch_bounds__(256) void hv_kernel(
    const float* __restrict__ x, const float* __restrict__ rwT,
    const float* __restrict__ betp, ushort* __restrict__ hv)
{
    const int lane = threadIdx.x & 63;
    const int q    = __builtin_amdgcn_readfirstlane(threadIdx.x >> 6);
    const int p    = blockIdx.x * 64 + lane;     // global pixel
    const int b    = p >> 12;
    const int hw   = p & 4095;

    float acc[16];
    #pragma unroll
    for (int j = 0; j < 16; ++j) acc[j] = betp[q * 16 + j];

    const float* xp = x + (size_t)b * C_ * HW_ + hw;
    #pragma unroll 4
    for (int k = 0; k < C_; ++k) {
        float xk = xp[(size_t)k * HW_];
        const float* rw = rwT + k * HID_ + q * 16;   // uniform -> scalar loads
        #pragma unroll
        for (int j = 0; j < 16; ++j) acc[j] = fmaf(xk, rw[j], acc[j]);
    }
    union { ushort s[16]; uint4 v[2]; } u;
    #pragma unroll
    for (int j = 0; j < 16; ++j) u.s[j] = f2bf(fmaxf(acc[j], 0.f));
    uint4* dst = (uint4*)(hv + (size_t)p * HID_ + q * 16);
    dst[0] = u.v[0];
    dst[1] = u.v[1];
}

// ---------------------------------------------------------------- main ----
// Block: one image row (64 px) x 16 groups. Wave w handles group
// gy*16 + iter*4 + w. MFMA 16x16x32 bf16: A = hv (px x k), B = kwb (k x tap).
__global__ __launch_bounds__(256) void invol_main(
    const float* __restrict__ x, const ushort* __restrict__ hv,
    const ushort* __restrict__ kwb, const float* __restrict__ kb,
    float* __restrict__ out)
{
    __shared__ ushort hv_s[64 * HID_];        // 8 KB, XOR-swizzled rows
    __shared__ float  ker_s[4 * 64 * KK_];    // 50176 B, per-wave private

    const int tid  = threadIdx.x;
    const int lane = tid & 63;
    const int wave = __builtin_amdgcn_readfirstlane(tid >> 6);
    const int b = blockIdx.x >> 6;
    const int y = blockIdx.x & 63;
    const int rowpix = (b << 12) + (y << 6);  // global pixel of px=0

    // stage hv row tile: row byte-addr ^= (row&7)<<4 (breaks 128B-stride banks)
    {
        int px = tid >> 2, c = tid & 3;
        const uint4* src = (const uint4*)(hv + (size_t)(rowpix + px) * HID_ + c * 16);
        int d0 = (px * 128 + c * 32) ^ ((px & 7) << 4);
        int d1 = (px * 128 + c * 32 + 16) ^ ((px & 7) << 4);
        *(uint4*)((char*)hv_s + d0) = src[0];
        *(uint4*)((char*)hv_s + d1) = src[1];
    }
    __syncthreads();

    const int l15 = lane & 15;
    const int l4  = lane >> 4;

    for (int iter = 0; iter < 4; ++iter) {
        const int g = blockIdx.y * 16 + iter * 4 + wave;

        // A frags: lane holds A[row=l15+16mi][k=ks*32+l4*8+j]
        bf16x8 af[2][4];
        #pragma unroll
        for (int ks = 0; ks < 2; ++ks)
            #pragma unroll
            for (int mi = 0; mi < 4; ++mi) {
                int row  = mi * 16 + l15;
                int byte = (row * 128 + ks * 64 + l4 * 16) ^ ((row & 7) << 4);
                af[ks][mi] = *(const bf16x8*)((const char*)hv_s + byte);
            }
        // B frags: lane holds B[k=ks*32+l4*8+j][col=l15+16ni] = kwb[g][col][k]
        bf16x8 bfg[2][4];
        const char* kwg = (const char*)kwb + (size_t)g * 8192;
        #pragma unroll
        for (int ks = 0; ks < 2; ++ks)
            #pragma unroll
            for (int ni = 0; ni < 4; ++ni) {
                int byte = (ni * 16 + l15) * 128 + ks * 64 + l4 * 16;
                bfg[ks][ni] = *(const bf16x8*)(kwg + byte);
            }

        f32x4 acc[4][4];
        #pragma unroll
        for (int mi = 0; mi < 4; ++mi)
            #pragma unroll
            for (int ni = 0; ni < 4; ++ni)
                acc[mi][ni] = (f32x4)(0.f);
        #pragma unroll
        for (int ks = 0; ks < 2; ++ks)
            #pragma unroll
            for (int mi = 0; mi < 4; ++mi)
                #pragma unroll
                for (int ni = 0; ni < 4; ++ni)
                    acc[mi][ni] = __builtin_amdgcn_mfma_f32_16x16x32_bf16(
                        af[ks][mi], bfg[ks][ni], acc[mi][ni], 0, 0, 0);

        // bias + scatter to ker_s: D elem (mi,ni,r) is px=mi*16+l4*4+r, t=ni*16+l15
        float* kerw = ker_s + wave * (64 * KK_);
        #pragma unroll
        for (int ni = 0; ni < 4; ++ni) {
            int t = ni * 16 + l15;
            if (t < KK_) {
                float bias = kb[g * KK_ + t];
                #pragma unroll
                for (int mi = 0; mi < 4; ++mi)
                    #pragma unroll
                    for (int r = 0; r < 4; ++r) {
                        int px = mi * 16 + l4 * 4 + r;
                        kerw[px * KK_ + t] = acc[mi][ni][r] + bias;
                    }
            }
        }
        __syncthreads();

        // read back (lane == px; row stride 49 f32, odd -> <=2-way conflicts)
        float kv[KK_];
        const float* kerr = ker_s + wave * (64 * KK_) + lane * KK_;
        #pragma unroll
        for (int t = 0; t < KK_; ++t) kv[t] = kerr[t];
        float mean = 0.f;
        #pragma unroll
        for (int t = 0; t < KK_; ++t) mean += kv[t];
        mean *= (1.f / 49.f);
        float ss = 0.f;
        #pragma unroll
        for (int t = 0; t < KK_; ++t) { kv[t] -= mean; ss = fmaf(kv[t], kv[t], ss); }
        float invn = 1.f / fmaxf(sqrtf(ss), 1e-6f);

        // involution: coalesced x row loads, clamped cols, uniform row skip
        const float* xg = x + ((size_t)(b * G_ + g)) * HW_;
        float oacc = 0.f;
        #pragma unroll
        for (int i = 0; i < KS_; ++i) {
            int yy = y + i - 3;
            if ((unsigned)yy < (unsigned)H_) {
                const float* xr = xg + yy * W_;
                #pragma unroll
                for (int j = 0; j < KS_; ++j) {
                    int col = lane + j - 3;
                    bool ok = (unsigned)col < (unsigned)W_;
                    float v = xr[ok ? col : 0];
                    oacc = fmaf(ok ? v : 0.f, kv[i * KS_ + j], oacc);
                }
            }
        }
        out[((size_t)(b * G_ + g)) * HW_ + y * W_ + lane] = oacc * invn;
    }
}

// ---------------------------------------------------- fallback (R2 code) ----
__global__ __launch_bounds__(256) void invol_fallback(
    const float* __restrict__ x, const float* __restrict__ reduce_w,
    const float* __restrict__ bn_gamma, const float* __restrict__ bn_beta,
    const float* __restrict__ bn_mean, const float* __restrict__ bn_var,
    const float* __restrict__ kw, const float* __restrict__ kb,
    float* __restrict__ out)
{
    __shared__ float rwT[C_][HID_ + 4];
    __shared__ float bns[HID_];
    __shared__ float bnb[HID_];
    const int tid = threadIdx.x;
    const int b  = blockIdx.z;
    const int g0 = blockIdx.y * 32;
    const int p  = blockIdx.x * 256 + tid;
    const int py = p >> 6;
    const int px = p & 63;
    #pragma unroll 1
    for (int o = 0; o < HID_; ++o) rwT[tid][o] = reduce_w[o * C_ + tid];
    if (tid < HID_) {
        float inv = bn_gamma[tid] * rsqrtf(bn_var[tid] + BN_EPS);
        bns[tid] = inv;
        bnb[tid] = bn_beta[tid] - bn_mean[tid] * inv;
    }
    __syncthreads();
    float hvv[HID_];
    #pragma unroll
    for (int o = 0; o < HID_; ++o) hvv[o] = 0.f;
    const float* xb = x + (size_t)b * C_ * HW_ + p;
    #pragma unroll 4
    for (int k = 0; k < C_; ++k) {
        float xk = xb[(size_t)k * HW_];
        const float4* wr = (const float4*)&rwT[k][0];
        #pragma unroll
        for (int o4 = 0; o4 < HID_ / 4; ++o4) {
            float4 w = wr[o4];
            hvv[o4*4+0] = fmaf(xk, w.x, hvv[o4*4+0]);
            hvv[o4*4+1] = fmaf(xk, w.y, hvv[o4*4+1]);
            hvv[o4*4+2] = fmaf(xk, w.z, hvv[o4*4+2]);
            hvv[o4*4+3] = fmaf(xk, w.w, hvv[o4*4+3]);
        }
    }
    #pragma unroll
    for (int o = 0; o < HID_; ++o) hvv[o] = fmaxf(fmaf(hvv[o], bns[o], bnb[o]), 0.f);
    #pragma unroll 1
    for (int gi = 0; gi < 32; ++gi) {
        const int g = g0 + gi;
        const float* kwg = kw + (size_t)g * KK_ * HID_;
        float acc[KK_];
        #pragma unroll
        for (int t = 0; t < KK_; ++t) {
            float a = kb[g * KK_ + t];
            const float4* row = (const float4*)(kwg + t * HID_);
            #pragma unroll
            for (int k4 = 0; k4 < HID_ / 4; ++k4) {
                float4 w = row[k4];
                a = fmaf(w.x, hvv[k4*4+0], a);
                a = fmaf(w.y, hvv[k4*4+1], a);
                a = fmaf(w.z, hvv[k4*4+2], a);
                a = fmaf(w.w, hvv[k4*4+3], a);
            }
            acc[t] = a;
        }
        float mean = 0.f;
        #pragma unroll
        for (int t = 0; t < KK_; ++t) mean += acc[t];
        mean *= (1.f / 49.f);
        float ss = 0.f;
        #pragma unroll
        for (int t = 0; t < KK_; ++t) { acc[t] -= mean; ss = fmaf(acc[t], acc[t], ss); }
        float inv = 1.f / fmaxf(sqrtf(ss), 1e-6f);
        const float* xg = x + ((size_t)(b * G_ + g)) * HW_;
        float oacc = 0.f;
        #pragma unroll
        for (int i = 0; i < KS_; ++i) {
            int yv = py + i - 3;
            bool rok = ((unsigned)yv < (unsigned)H_);
            const float* xrow = xg + yv * W_;
            #pragma unroll
            for (int j = 0; j < KS_; ++j) {
                int xx = px + j - 3;
                bool ok = rok && ((unsigned)xx < (unsigned)W_);
                float v = ok ? xrow[xx] : 0.f;
                oacc = fmaf(v, acc[i*7+j], oacc);
            }
        }
        out[((size_t)(b * G_ + g)) * HW_ + p] = oacc * inv;
    }
}

extern "C" void kernel_launch(void* const* d_in, const int* in_sizes, int n_in,
                              void* d_out, int out_size, void* d_ws, size_t ws_size,
                              hipStream_t stream) {
    const float* x        = (const float*)d_in[0];
    const float* reduce_w = (const float*)d_in[1];
    const float* bn_gamma = (const float*)d_in[2];
    const float* bn_beta  = (const float*)d_in[3];
    const float* bn_mean  = (const float*)d_in[4];
    const float* bn_var   = (const float*)d_in[5];
    const float* kproj_w  = (const float*)d_in[6];
    const float* kproj_b  = (const float*)d_in[7];
    float* out = (float*)d_out;
    const int B = in_sizes[0] / (C_ * HW_);

    size_t kwb_off = 0;
    size_t kwb_sz  = (size_t)G_ * 64 * 64 * 2;       // 2 MB
    size_t hv_off  = kwb_off + kwb_sz;
    size_t hv_sz   = (size_t)B * HW_ * HID_ * 2;     // B*512 KB
    size_t rwt_off = hv_off + hv_sz;
    size_t rwt_sz  = (size_t)C_ * HID_ * 4;          // 64 KB
    size_t bet_off = rwt_off + rwt_sz;
    size_t need    = bet_off + (size_t)HID_ * 4;

    if (ws_size < need) {
        dim3 grid(HW_ / 256, G_ / 32, B);
        invol_fallback<<<grid, 256, 0, stream>>>(x, reduce_w, bn_gamma, bn_beta,
                                                 bn_mean, bn_var, kproj_w, kproj_b, out);
        return;
    }

    ushort* kwb  = (ushort*)((char*)d_ws + kwb_off);
    ushort* hv   = (ushort*)((char*)d_ws + hv_off);
    float*  rwT  = (float*)((char*)d_ws + rwt_off);
    float*  betp = (float*)((char*)d_ws + bet_off);

    prep_kernel<<<dim3(257), 256, 0, stream>>>(kproj_w, reduce_w, bn_gamma, bn_beta,
                                               bn_mean, bn_var, kwb, rwT, betp);
    hv_kernel<<<dim3(B * HW_ / 64), 256, 0, stream>>>(x, rwT, betp, hv);
    invol_main<<<dim3(B * H_, 16), 256, 0, stream>>>(x, hv, kwb, kproj_b, out);
}